// Round 7
// baseline (73.963 us; speedup 1.0000x reference)
//
#include <hip/hip_runtime.h>
#include <math.h>

#define BB 4
#define C 64
#define H 128
#define W 128
#define K 9
#define HW (H*W)
#define KC 576           // GEMM K dim: col = k*64 + c
#define KH 288           // K-split half
#define PIX 32           // pixels per block
#define ROWB 592         // LDS staging row bytes: 288*2 + 16 pad
#define OFFW 36          // offbuf row stride in f32

typedef __attribute__((ext_vector_type(4))) float f32x4;
typedef __attribute__((ext_vector_type(8))) _Float16 f16x8;

static __device__ __forceinline__ f16x8 splat8(float f) {
  _Float16 h = (_Float16)f;
  f16x8 v = {h, h, h, h, h, h, h, h};
  return v;
}

// ---------------- kernel 1: transpose x,c to NHWC f16 + weight prep (folded)
__global__ __launch_bounds__(256) void xpose_prep_kernel(
    const float* __restrict__ x, const float* __restrict__ cin,
    const float* __restrict__ wd, const float* __restrict__ woff,
    _Float16* __restrict__ xt, _Float16* __restrict__ ct,
    _Float16* __restrict__ wtb, _Float16* __restrict__ wotb) {
  __shared__ _Float16 lds16[32 * 72];
  int t = threadIdx.x;

  if (blockIdx.y == 1 && blockIdx.x < 144) {
    int i = blockIdx.x * 256 + t;
    if (i < C * KC) {           // wtb [64][576] <- w_dcn, col = k*64+c
      int o = i / KC, r = i % KC, k = r >> 6, c = r & 63;
      wtb[i] = (_Float16)wd[(o * C + c) * 9 + k];
    }
    if (i < 32 * KC) {          // wotb [32][576] <- w_off, rows 27..31 = 0
      int o = i / KC, r = i % KC, t9 = r >> 6, c = r & 63;
      wotb[i] = (o < 27) ? (_Float16)woff[(o * C + c) * 9 + t9] : (_Float16)0.f;
    }
  }

  const float* src = blockIdx.y ? cin : x;
  _Float16* dst = blockIdx.y ? ct : xt;

  int P0 = blockIdx.x * 32;
  int b = P0 >> 14;
  int pp0 = P0 & (HW - 1);

  int p = t & 31;
  int cg = t >> 5;
  const float* xb = src + (size_t)b * C * HW + pp0 + p;
  f16x8 u;
#pragma unroll
  for (int j = 0; j < 8; ++j)
    u[j] = (_Float16)xb[(cg * 8 + j) * HW];
  *(f16x8*)(lds16 + p * 72 + ((cg ^ (p & 7)) << 3)) = u;

  __syncthreads();

  int q = t >> 3;
  int s = t & 7;
  f16x8 v = *(const f16x8*)(lds16 + q * 72 + ((s ^ (q & 7)) << 3));
  *(f16x8*)(dst + (size_t)(P0 + q) * 64 + s * 8) = v;
}

// ---------------- kernel 2: fused conv_offset + modulated deformable conv
// 32 pixels/block, 4 waves, K-split staging (288 cols at a time) -> 8 blk/CU
__global__ __launch_bounds__(256, 8) void dcn_fused_kernel(
    const _Float16* __restrict__ xt, const _Float16* __restrict__ ct,
    const _Float16* __restrict__ wtb, const _Float16* __restrict__ wotb,
    const float* __restrict__ boff, const float* __restrict__ bd,
    float* __restrict__ out) {
  __shared__ __align__(16) unsigned char smem[PIX * ROWB];  // 18944 B
  float* offbuf = (float*)smem;                             // [32][OFFW] reuse

  int tid = threadIdx.x;
  int bid = blockIdx.x;

  int p  = tid >> 3;            // pixel 0..31   (8 lanes per pixel)
  int cg = tid & 7;             // channel group 0..7
  int pix = bid * PIX + p;
  int w = pix & (W - 1);
  int h = (pix >> 7) & (H - 1);
  int b = pix >> 14;

  int lane = tid & 63;
  int wv = tid >> 6;
  int lr = lane & 15, lh = lane >> 4;
  int swzp = ((p >> 3) & 3) << 4;      // XOR bits 4-5 only (stays in 64B block)

  // ---- stage A (half): c-tile im2col cols [half*288, half*288+288) ----
  auto stageA = [&](int half) {
    const _Float16* cb = ct + (size_t)b * HW * 64 + cg * 8;
#pragma unroll
    for (int t9 = 0; t9 < 9; ++t9) {
      if (half == 0 && t9 > 4) continue;
      if (half == 1 && t9 < 4) continue;
      int gc = t9 * 64 + cg * 8;
      bool mine = half ? (gc >= KH) : (gc < KH);
      if (mine) {
        int yy = h + t9 / 3 - 1;
        int xx = w + t9 % 3 - 1;
        bool ok = (yy >= 0) && (yy < H) && (xx >= 0) && (xx < W);
        f16x8 v = {};
        if (ok) v = *(const f16x8*)(cb + (size_t)(yy * W + xx) * 64);
        int colB = ((gc - half * KH) * 2) ^ swzp;
        *(f16x8*)(smem + p * ROWB + colB) = v;
      }
    }
  };

  // ======== GEMM1: off[32o][32p] = wotb[32][576] @ ctile ========
  int otile = wv & 1;
  int nh = wv >> 1;
  int n1r = nh * 16 + lr;
  int swz1 = ((n1r >> 3) & 3) << 4;
  const _Float16* arow = wotb + (otile * 16 + lr) * KC + lh * 8;
  f32x4 acc = {0.f, 0.f, 0.f, 0.f};

  stageA(0);
  __syncthreads();
#pragma unroll 1
  for (int kb = 0; kb < 9; ++kb) {
    f16x8 a = *(const f16x8*)(arow + kb * 32);
    f16x8 bf = *(const f16x8*)(smem + n1r * ROWB + ((kb * 64 + lh * 16) ^ swz1));
    acc = __builtin_amdgcn_mfma_f32_16x16x32_f16(a, bf, acc, 0, 0, 0);
  }
  __syncthreads();
  stageA(1);
  __syncthreads();
#pragma unroll 1
  for (int kb = 9; kb < 18; ++kb) {
    f16x8 a = *(const f16x8*)(arow + kb * 32);
    f16x8 bf = *(const f16x8*)(smem + n1r * ROWB + (((kb - 9) * 64 + lh * 16) ^ swz1));
    acc = __builtin_amdgcn_mfma_f32_16x16x32_f16(a, bf, acc, 0, 0, 0);
  }
  __syncthreads();

  // write offbuf[p][o] = acc + boff
  {
    int obase = otile * 16 + lh * 4;
    f32x4 v;
#pragma unroll
    for (int r = 0; r < 4; ++r) {
      int o = obase + r;
      v[r] = acc[r] + ((o < 27) ? boff[o] : 0.f);
    }
    *(f32x4*)(offbuf + n1r * OFFW + obase) = v;
  }
  __syncthreads();

  // pull this pixel's 27 offset/mask values into registers
  f32x4 rv[7];
#pragma unroll
  for (int j = 0; j < 7; ++j)
    rv[j] = *(const f32x4*)(offbuf + p * OFFW + 4 * j);
  __syncthreads();

#define OFFV(i) (rv[(i) >> 2][(i) & 3])

  // ---- stage B (half): bilinear sample x, cols [half*288, half*288+288) ----
  auto stageB = [&](int half) {
    const _Float16* xtb = xt + (size_t)b * HW * 64 + cg * 8;
#pragma unroll
    for (int k = 0; k < 9; ++k) {
      if (half == 0 && k > 4) continue;
      if (half == 1 && k < 4) continue;
      int gc = k * 64 + cg * 8;
      bool mine = half ? (gc >= KH) : (gc < KH);
      if (mine) {
        float dy = OFFV(2 * k);
        float dx = OFFV(2 * k + 1);
        float mv = OFFV(18 + k);
        float m = 1.0f / (1.0f + __expf(-mv));

        float py = (float)(h + k / 3 - 1) + dy;
        float px = (float)(w + k % 3 - 1) + dx;
        float y0f = floorf(py), x0f = floorf(px);
        int y0 = (int)y0f, x0 = (int)x0f;
        float wy1 = py - y0f, wx1 = px - x0f;
        float wy0 = 1.0f - wy1, wx0 = 1.0f - wx1;

        bool y0v = (y0 >= 0) && (y0 < H);
        bool y1v = (y0 + 1 >= 0) && (y0 + 1 < H);
        bool x0v = (x0 >= 0) && (x0 < W);
        bool x1v = (x0 + 1 >= 0) && (x0 + 1 < W);
        int y0c = min(max(y0, 0), H - 1), y1c = min(max(y0 + 1, 0), H - 1);
        int x0c = min(max(x0, 0), W - 1), x1c = min(max(x0 + 1, 0), W - 1);

        float w00 = wy0 * wx0 * (float)(y0v && x0v) * m;
        float w01 = wy0 * wx1 * (float)(y0v && x1v) * m;
        float w10 = wy1 * wx0 * (float)(y1v && x0v) * m;
        float w11 = wy1 * wx1 * (float)(y1v && x1v) * m;

        f16x8 c00 = *(const f16x8*)(xtb + (size_t)(y0c * W + x0c) * 64);
        f16x8 c01 = *(const f16x8*)(xtb + (size_t)(y0c * W + x1c) * 64);
        f16x8 c10 = *(const f16x8*)(xtb + (size_t)(y1c * W + x0c) * 64);
        f16x8 c11 = *(const f16x8*)(xtb + (size_t)(y1c * W + x1c) * 64);

        f16x8 s = c00 * splat8(w00);
        s += c01 * splat8(w01);
        s += c10 * splat8(w10);
        s += c11 * splat8(w11);

        int colB = ((gc - half * KH) * 2) ^ swzp;
        *(f16x8*)(smem + p * ROWB + colB) = s;
      }
    }
  };

  // ======== GEMM2: out[64o][32p] = wtb[64][576] @ samp ========
  int n0 = lr, n1 = 16 + lr;
  int swzA = ((n0 >> 3) & 3) << 4;
  int swzB = ((n1 >> 3) & 3) << 4;
  const _Float16* wrow = wtb + (wv * 16 + lr) * KC + lh * 8;

  f32x4 acc0 = {0.f, 0.f, 0.f, 0.f};
  f32x4 acc1 = {0.f, 0.f, 0.f, 0.f};

  stageB(0);
  __syncthreads();
#pragma unroll 1
  for (int kb = 0; kb < 9; ++kb) {
    f16x8 a = *(const f16x8*)(wrow + kb * 32);
    f16x8 b0 = *(const f16x8*)(smem + n0 * ROWB + ((kb * 64 + lh * 16) ^ swzA));
    acc0 = __builtin_amdgcn_mfma_f32_16x16x32_f16(a, b0, acc0, 0, 0, 0);
    f16x8 b1 = *(const f16x8*)(smem + n1 * ROWB + ((kb * 64 + lh * 16) ^ swzB));
    acc1 = __builtin_amdgcn_mfma_f32_16x16x32_f16(a, b1, acc1, 0, 0, 0);
  }
  __syncthreads();
  stageB(1);
  __syncthreads();
#pragma unroll 1
  for (int kb = 9; kb < 18; ++kb) {
    f16x8 a = *(const f16x8*)(wrow + kb * 32);
    f16x8 b0 = *(const f16x8*)(smem + n0 * ROWB + (((kb - 9) * 64 + lh * 16) ^ swzA));
    acc0 = __builtin_amdgcn_mfma_f32_16x16x32_f16(a, b0, acc0, 0, 0, 0);
    f16x8 b1 = *(const f16x8*)(smem + n1 * ROWB + (((kb - 9) * 64 + lh * 16) ^ swzB));
    acc1 = __builtin_amdgcn_mfma_f32_16x16x32_f16(a, b1, acc1, 0, 0, 0);
  }

  // ---- epilogue ----
  int pp0 = (bid * PIX) & (HW - 1);
#pragma unroll
  for (int r = 0; r < 4; ++r) {
    int o = wv * 16 + lh * 4 + r;
    float bias = bd[o];
    size_t base = ((size_t)(b * C + o)) * HW + pp0 + lr;
    out[base]      = acc0[r] + bias;
    out[base + 16] = acc1[r] + bias;
  }
}

extern "C" void kernel_launch(void* const* d_in, const int* in_sizes, int n_in,
                              void* d_out, int out_size, void* d_ws, size_t ws_size,
                              hipStream_t stream) {
  const float* x    = (const float*)d_in[0];
  const float* c    = (const float*)d_in[1];
  const float* woff = (const float*)d_in[2];
  const float* boff = (const float*)d_in[3];
  const float* wdcn = (const float*)d_in[4];
  const float* bdcn = (const float*)d_in[5];
  float* out = (float*)d_out;

  _Float16* xt   = (_Float16*)d_ws;                   // 4,194,304 f16
  _Float16* ct   = xt + 4194304;                      // 4,194,304 f16
  _Float16* wtb  = ct + 4194304;                      // 36,864 f16
  _Float16* wotb = wtb + 36864;                       // 18,432 f16

  int npix = BB * H * W;                              // 65536
  dim3 gx(npix / 32, 2);
  xpose_prep_kernel<<<gx, 256, 0, stream>>>(x, c, wdcn, woff, xt, ct, wtb, wotb);
  dcn_fused_kernel<<<npix / PIX, 256, 0, stream>>>(xt, ct, wtb, wotb, boff, bdcn, out);
}